// Round 15
// baseline (136.376 us; speedup 1.0000x reference)
//
#include <hip/hip_runtime.h>

// Problem constants (from setup_inputs): B=4, N=16384, E=262144, F=64
#define BB 4
#define NN 16384
#define EE 262144          // 2^18
#define FF 64
#define ROWS (BB * NN)     // 65536
#define CAP 64             // slots per destination row (P(deg>64) ~ 0)
#define CHUNKS 64          // edge chunks per batch
#define CHUNK_E (EE / CHUNKS)   // 4096 edges per chunk
#define TILE_R 256         // rows per scan block
#define HALF_R (NN / 2)    // 8192 rows per scatter half-split
#define QUART_R (NN / 4)   // 4096 rows per hist quarter-split

typedef __bf16 bf16x8 __attribute__((ext_vector_type(8)));
typedef float  f32x4  __attribute__((ext_vector_type(4)));

__device__ __forceinline__ unsigned short f32_to_bf16(float f) {
    unsigned int u = __float_as_uint(f);
    u += 0x7FFFu + ((u >> 16) & 1u);   // RNE
    return (unsigned short)(u >> 16);
}

// ---------------------------------------------------------------------------
// Kernel 1: fused MFMA + quarter-row hist. Grid 1024 x 256 (R10's exact mfma
// geometry; 16.5 KB LDS -> 8 blocks/CU = 32 waves/CU).
//   Phase A (all 4 waves): one 16-row MFMA tile each (waveId = blk*4+w =
//     R10's formula, bit-identical Wh/sc/sn) from fp32 h regs + wc/wn LDS.
//   Phase B: histogram chunk (b,c) over a 4096-row QUARTER (16 KB LDS;
//     g = (b, c, quarter)); each chunk is read by 4 blocks (~32 MB L2, ~1us).
//   histG layout unchanged -> scan/scatter untouched. Inactive chunks skip
//   phase B only (block-uniform).
// ---------------------------------------------------------------------------
__global__ __launch_bounds__(256) void mfma_hist_kernel(
    const float* __restrict__ h, const float* __restrict__ W,
    const float* __restrict__ a,
    const int* __restrict__ edge, const int* __restrict__ edge_num,
    unsigned short* __restrict__ Wh,
    float* __restrict__ sc, float* __restrict__ sn,
    unsigned short* __restrict__ histG)
{
    __shared__ float wc[FF], wn[FF];
    __shared__ unsigned int hist[QUART_R];     // 16 KB
    const int t = threadIdx.x;
    const int lane = t & 63;
    const int m = lane & 15;
    const int q = lane >> 4;

    const int g = blockIdx.x;                  // [0, 1024)
    const int b = g >> 8;                      // batch
    const int c = (g >> 2) & (CHUNKS - 1);     // chunk
    const int quarter = g & 3;                 // row quarter
    const int en = edge_num[b];
    const int e0 = c * CHUNK_E;
    const bool active = (e0 < en);             // block-uniform

    if (t < 128) {                             // threads 0-63: wc, 64-127: wn
        const int f = t & 63;
        const float* av = a + (t >> 6) * FF;
        float s = 0.0f;
        #pragma unroll 8
        for (int o = 0; o < FF; ++o)
            s = fmaf(av[o], W[o * FF + f], s);
        (t < 64 ? wc : wn)[f] = s;
    }
    for (int r = t; r < QUART_R; r += 256) hist[r] = 0u;   // 16 iters

    // ---- B fragments: 4 n-tiles x 2 k-halves, in registers ---------------
    bf16x8 bfrag[4][2];
    #pragma unroll
    for (int nt = 0; nt < 4; ++nt) {
        const float* wr = W + (nt * 16 + m) * FF;
        #pragma unroll
        for (int kh = 0; kh < 2; ++kh) {
            const float4 v0 = *(const float4*)(wr + kh * 32 + q * 8);
            const float4 v1 = *(const float4*)(wr + kh * 32 + q * 8 + 4);
            bf16x8 bb;
            bb[0] = (__bf16)v0.x; bb[1] = (__bf16)v0.y;
            bb[2] = (__bf16)v0.z; bb[3] = (__bf16)v0.w;
            bb[4] = (__bf16)v1.x; bb[5] = (__bf16)v1.y;
            bb[6] = (__bf16)v1.z; bb[7] = (__bf16)v1.w;
            bfrag[nt][kh] = bb;
        }
    }

    __syncthreads();                           // wc/wn ready AND hist zeroed

    // ---- Phase A: one 16-row tile per wave (R10 formula) ------------------
    {
        const int waveId = g * 4 + (t >> 6);   // [0, 4096)
        const int R0 = waveId * 16;
        const float* hr = h + (size_t)(R0 + m) * FF;
        bf16x8 af[2];
        float s1 = 0.0f, s2 = 0.0f;            // partial sc/sn, 16 feats/lane
        #pragma unroll
        for (int kh = 0; kh < 2; ++kh) {
            const float4 v0 = *(const float4*)(hr + kh * 32 + q * 8);
            const float4 v1 = *(const float4*)(hr + kh * 32 + q * 8 + 4);
            bf16x8 aa;
            aa[0] = (__bf16)v0.x; aa[1] = (__bf16)v0.y;
            aa[2] = (__bf16)v0.z; aa[3] = (__bf16)v0.w;
            aa[4] = (__bf16)v1.x; aa[5] = (__bf16)v1.y;
            aa[6] = (__bf16)v1.z; aa[7] = (__bf16)v1.w;
            af[kh] = aa;
            const int fb = kh * 32 + q * 8;
            const float4 c0 = *(const float4*)&wc[fb];
            const float4 c1 = *(const float4*)&wc[fb + 4];
            const float4 n0 = *(const float4*)&wn[fb];
            const float4 n1 = *(const float4*)&wn[fb + 4];
            s1 = fmaf(v0.x, c0.x, fmaf(v0.y, c0.y, fmaf(v0.z, c0.z, fmaf(v0.w, c0.w, s1))));
            s1 = fmaf(v1.x, c1.x, fmaf(v1.y, c1.y, fmaf(v1.z, c1.z, fmaf(v1.w, c1.w, s1))));
            s2 = fmaf(v0.x, n0.x, fmaf(v0.y, n0.y, fmaf(v0.z, n0.z, fmaf(v0.w, n0.w, s2))));
            s2 = fmaf(v1.x, n1.x, fmaf(v1.y, n1.y, fmaf(v1.z, n1.z, fmaf(v1.w, n1.w, s2))));
        }
        s1 += __shfl_xor(s1, 16); s2 += __shfl_xor(s2, 16);
        s1 += __shfl_xor(s1, 32); s2 += __shfl_xor(s2, 32);
        if (lane < 16) { sc[R0 + m] = s1; sn[R0 + m] = s2; }

        #pragma unroll
        for (int nt = 0; nt < 4; ++nt) {
            f32x4 acc = {0.f, 0.f, 0.f, 0.f};
            acc = __builtin_amdgcn_mfma_f32_16x16x32_bf16(af[0], bfrag[nt][0], acc, 0, 0, 0);
            acc = __builtin_amdgcn_mfma_f32_16x16x32_bf16(af[1], bfrag[nt][1], acc, 0, 0, 0);
            #pragma unroll
            for (int i = 0; i < 4; ++i)
                Wh[(size_t)(R0 + q * 4 + i) * FF + nt * 16 + m] = f32_to_bf16(acc[i]);
        }
    }

    // ---- Phase B: histogram chunk (b,c) over row quarter ------------------
    if (active) {
        const int2* ep = (const int2*)edge + (size_t)b * EE + e0;
        const int nAct = min(en - e0, CHUNK_E);
        for (int j = t; j < nAct; j += 256) {  // 16 iters
            const int2 e2 = ep[j];
            if ((e2.x >> 12) == quarter)       // row in my quarter
                atomicAdd(&hist[e2.x & (QUART_R - 1)], 1u);   // LDS atomic
        }
        __syncthreads();

        ushort2* out2 = (ushort2*)(histG + (size_t)(b * CHUNKS + c) * NN + quarter * QUART_R);
        for (int r2 = t; r2 < QUART_R / 2; r2 += 256) {  // 4B coalesced
            ushort2 v;
            v.x = (unsigned short)hist[2 * r2];
            v.y = (unsigned short)hist[2 * r2 + 1];
            out2[r2] = v;
        }
    }
}

// ---------------------------------------------------------------------------
// Kernel 2: scan — per row, exclusive prefix over the ACTIVE chunk counts
// (in-place histG -> u16 sat bases) + total cnt[row]. R10/R14 version.
// ---------------------------------------------------------------------------
__global__ __launch_bounds__(256) void scan_kernel(
    const int* __restrict__ edge_num,
    unsigned short* __restrict__ histG, int* __restrict__ cnt)
{
    __shared__ unsigned short tile[CHUNKS][TILE_R];   // 32 KB
    const int g = blockIdx.x;                  // [0, 256) = 4 batches x 64 tiles
    const int b = g >> 6, tl = g & 63;
    const int r0 = tl * TILE_R;
    const int t = threadIdx.x;
    const int en = edge_num[b];
    const int nact = min((en + CHUNK_E - 1) / CHUNK_E, CHUNKS);

    for (int c = 0; c < nact; ++c)
        tile[c][t] = histG[(size_t)(b * CHUNKS + c) * NN + r0 + t];
    __syncthreads();

    unsigned int acc = 0;                      // thread t owns row r0+t
    for (int c = 0; c < nact; ++c) {
        const unsigned int v = tile[c][t];
        tile[c][t] = (unsigned short)(acc > 65535u ? 65535u : acc);
        acc += v;
    }
    cnt[b * NN + r0 + t] = (int)acc;

    for (int c = 0; c < nact; ++c)
        histG[(size_t)(b * CHUNKS + c) * NN + r0 + t] = tile[c][t];
}

// ---------------------------------------------------------------------------
// Kernel 3: scatter + score, ROW-SPLIT (R14 version, unchanged). 512 blocks
// = (batch, chunk, half). slotA (32 KB) preloaded with scanned bases ->
// atomicAdd returns the dense slot; scL (32 KB) caches the half's sc slice.
// payload = (xe-hi18 | nbr-lo14).
// ---------------------------------------------------------------------------
__global__ __launch_bounds__(1024) void scatter_kernel(
    const int* __restrict__ edge, const int* __restrict__ edge_num,
    const unsigned short* __restrict__ baseG,
    const float* __restrict__ sc, const float* __restrict__ sn,
    const float* __restrict__ ew,
    unsigned int* __restrict__ payload)
{
    __shared__ unsigned int slotA[HALF_R];     // 32 KB
    __shared__ float scL[HALF_R];              // 32 KB
    const int g = blockIdx.x;                  // [0, 512)
    const int half = g & 1;
    const int c = (g >> 1) & (CHUNKS - 1);
    const int b = g >> 7;
    const int t = threadIdx.x;
    const int en = edge_num[b];
    const int e0 = c * CHUNK_E;
    if (e0 >= en) return;                      // block-uniform

    const int rbase = half * HALF_R;
    const ushort2* b2 = (const ushort2*)(baseG + (size_t)(b * CHUNKS + c) * NN + rbase);
    for (int r2 = t; r2 < HALF_R / 2; r2 += 1024) {  // coalesced
        const ushort2 v = b2[r2];
        slotA[2 * r2]     = v.x;
        slotA[2 * r2 + 1] = v.y;
    }
    const float* scH = sc + b * NN + rbase;
    for (int r = t; r < HALF_R; r += 1024)
        scL[r] = scH[r];
    __syncthreads();

    const int2* ep = (const int2*)edge + (size_t)b * EE + e0;
    const int nAct = min(en - e0, CHUNK_E);
    const float* snB = sn + b * NN;
    const float* ewB = ew + (size_t)b * EE + e0;   // coalesced: ewB[j]
    unsigned int* payB = payload + (size_t)b * NN * CAP;

    for (int j = t; j < nAct; j += 1024) {
        const int2 e2 = ep[j];
        if ((e2.x >> 13) != half) continue;    // row not in my half
        const int rl = e2.x & (HALF_R - 1);
        const float wgt = ewB[j];
        const float s0 = wgt * (scL[rl] + snB[e2.y]);
        const float s1 = s0 > 0.0f ? s0 : 0.01f * s0;
        const float xe = fminf(__expf(s1), 1000000.0f);
        const unsigned int slot = atomicAdd(&slotA[rl], 1u);     // base+rank
        if (slot < CAP)
            payB[(size_t)e2.x * CAP + slot] =
                ((__float_as_uint(xe) + 0x2000u) & 0xFFFFC000u) | (unsigned int)e2.y;
    }
}

// ---------------------------------------------------------------------------
// Kernel 4: gather v3 (proven R10 version, unchanged) — one row per 16-lane
// group (4 rows per wave). payload already holds packed (xe-hi18 | nbr-lo14).
// ---------------------------------------------------------------------------
__global__ __launch_bounds__(256) void gather_kernel(
    const int* __restrict__ cnt, const unsigned int* __restrict__ payload,
    const uint2* __restrict__ Wh2,             // bf16 quads
    float* __restrict__ out)
{
    const int bi = blockIdx.x;                 // 4096 blocks
    const int xcd = bi & 7;
    const int batch = xcd >> 1;                // 2 XCDs per batch
    const int within = ((bi >> 3) << 1) | (xcd & 1);   // [0, 1024)
    const int w = threadIdx.x >> 6;            // wave 0..3
    const int lane = threadIdx.x & 63;
    const int r = lane >> 4;                   // row within quad
    const int f = lane & 15;                   // feature quad
    const int gbase = lane & 48;               // first lane of my group
    const int rq = within * 4 + w;             // row-quad within batch
    const int row = batch * NN + rq * 4 + r;

    const unsigned int* pl = payload + (size_t)row * CAP;
    const uint2* WhB = Wh2 + (size_t)batch * NN * 16;

    int deg = cnt[row];
    unsigned int raw = pl[f];                  // unconditional, bounds-safe
    if (deg > CAP) deg = CAP;

    int jmax = deg;
    jmax = max(jmax, __shfl_xor(jmax, 16));
    jmax = max(jmax, __shfl_xor(jmax, 32));

    float a0 = 0.f, a1 = 0.f, a2 = 0.f, a3 = 0.f, pdsum = 0.f;

    for (int base = 0; base < jmax; base += 16) {
        const unsigned int p = (base + f < deg) ? raw : 0u;
        pdsum += __uint_as_float(p & 0xFFFFC000u);

        unsigned int rawN = 0u;
        if (base + 16 < jmax) rawN = pl[base + 16 + f];

        const int lim = min(16, jmax - base);
        for (int j4 = 0; j4 < lim; j4 += 4) {
            const unsigned int pv0 = __shfl(p, gbase + j4 + 0);
            const unsigned int pv1 = __shfl(p, gbase + j4 + 1);
            const unsigned int pv2 = __shfl(p, gbase + j4 + 2);
            const unsigned int pv3 = __shfl(p, gbase + j4 + 3);
            const uint2 w0 = WhB[(size_t)(pv0 & 0x3FFFu) * 16 + f];
            const uint2 w1 = WhB[(size_t)(pv1 & 0x3FFFu) * 16 + f];
            const uint2 w2 = WhB[(size_t)(pv2 & 0x3FFFu) * 16 + f];
            const uint2 w3 = WhB[(size_t)(pv3 & 0x3FFFu) * 16 + f];
            const float xe0 = __uint_as_float(pv0 & 0xFFFFC000u);
            const float xe1 = __uint_as_float(pv1 & 0xFFFFC000u);
            const float xe2 = __uint_as_float(pv2 & 0xFFFFC000u);
            const float xe3 = __uint_as_float(pv3 & 0xFFFFC000u);
            a0 = fmaf(xe0, __uint_as_float(w0.x << 16),         a0);
            a1 = fmaf(xe0, __uint_as_float(w0.x & 0xFFFF0000u), a1);
            a2 = fmaf(xe0, __uint_as_float(w0.y << 16),         a2);
            a3 = fmaf(xe0, __uint_as_float(w0.y & 0xFFFF0000u), a3);
            a0 = fmaf(xe1, __uint_as_float(w1.x << 16),         a0);
            a1 = fmaf(xe1, __uint_as_float(w1.x & 0xFFFF0000u), a1);
            a2 = fmaf(xe1, __uint_as_float(w1.y << 16),         a2);
            a3 = fmaf(xe1, __uint_as_float(w1.y & 0xFFFF0000u), a3);
            a0 = fmaf(xe2, __uint_as_float(w2.x << 16),         a0);
            a1 = fmaf(xe2, __uint_as_float(w2.x & 0xFFFF0000u), a1);
            a2 = fmaf(xe2, __uint_as_float(w2.y << 16),         a2);
            a3 = fmaf(xe2, __uint_as_float(w2.y & 0xFFFF0000u), a3);
            a0 = fmaf(xe3, __uint_as_float(w3.x << 16),         a0);
            a1 = fmaf(xe3, __uint_as_float(w3.x & 0xFFFF0000u), a1);
            a2 = fmaf(xe3, __uint_as_float(w3.y << 16),         a2);
            a3 = fmaf(xe3, __uint_as_float(w3.y & 0xFFFF0000u), a3);
        }
        raw = rawN;
    }

    pdsum += __shfl_xor(pdsum, 1);
    pdsum += __shfl_xor(pdsum, 2);
    pdsum += __shfl_xor(pdsum, 4);
    pdsum += __shfl_xor(pdsum, 8);

    const float inv = 1.0f / (1e-10f + pdsum);
    float4 o;
    o.x = fmaxf(a0 * inv, 0.0f);
    o.y = fmaxf(a1 * inv, 0.0f);
    o.z = fmaxf(a2 * inv, 0.0f);
    o.w = fmaxf(a3 * inv, 0.0f);
    ((float4*)out)[(size_t)row * 16 + f] = o;
}

extern "C" void kernel_launch(void* const* d_in, const int* in_sizes, int n_in,
                              void* d_out, int out_size, void* d_ws, size_t ws_size,
                              hipStream_t stream)
{
    const float* h        = (const float*)d_in[0];   // (B,N,F) f32
    const int*   edge     = (const int*)  d_in[1];   // (B,E,2) i32
    const int*   edge_num = (const int*)  d_in[2];   // (B,)    i32
    const float* ew       = (const float*)d_in[3];   // (B,E)   f32
    const float* W        = (const float*)d_in[4];   // (F,F)   f32
    const float* a        = (const float*)d_in[5];   // (1,2F)  f32
    float* out = (float*)d_out;                      // (B,N,F) f32

    // workspace layout — ~33 MB of the 256 MB d_ws
    unsigned short* Wh = (unsigned short*)d_ws;                 // 8 MB
    float* sc        = (float*)(Wh + (size_t)BB * NN * FF);     // 256 KB
    float* sn        = sc + ROWS;                               // 256 KB
    int*   cnt       = (int*)(sn + ROWS);                       // 256 KB
    unsigned int* payload = (unsigned int*)(cnt + ROWS);        // 16 MB
    unsigned short* histG = (unsigned short*)(payload + (size_t)ROWS * CAP); // 8 MB

    mfma_hist_kernel<<<1024, 256, 0, stream>>>(h, W, a, edge, edge_num,
                                               Wh, sc, sn, histG);

    scan_kernel<<<BB * (NN / TILE_R), 256, 0, stream>>>(edge_num, histG, cnt);

    scatter_kernel<<<BB * CHUNKS * 2, 1024, 0, stream>>>(edge, edge_num, histG,
                                                         sc, sn, ew, payload);

    gather_kernel<<<4096, 256, 0, stream>>>(cnt, payload,
                                            (const uint2*)Wh, out);
}

// Round 16
// 128.920 us; speedup vs baseline: 1.0578x; 1.0578x over previous
//
#include <hip/hip_runtime.h>

// Problem constants (from setup_inputs): B=4, N=16384, E=262144, F=64
#define BB 4
#define NN 16384
#define EE 262144          // 2^18
#define FF 64
#define ROWS (BB * NN)     // 65536
#define CAP 64             // slots per destination row (P(deg>64) ~ 0)
#define CHUNKS 64          // edge chunks per batch
#define CHUNK_E (EE / CHUNKS)   // 4096 edges per chunk
#define TILE_R 256         // rows per scan block
#define HALF_R (NN / 2)    // 8192 rows per hist/scatter half-split

typedef __bf16 bf16x8 __attribute__((ext_vector_type(8)));
typedef float  f32x4  __attribute__((ext_vector_type(4)));

__device__ __forceinline__ unsigned short f32_to_bf16(float f) {
    unsigned int u = __float_as_uint(f);
    u += 0x7FFFu + ((u >> 16) & 1u);   // RNE
    return (unsigned short)(u >> 16);
}

// ---------------------------------------------------------------------------
// Kernel 1: hist, ROW-SPLIT (R14 version, verbatim). 512 blocks =
// (batch, chunk, row-half). 32 KB LDS -> 2 blocks/CU by wave cap,
// 32 resident waves/CU. Writes its half of the u16 histG chunk vector.
// ---------------------------------------------------------------------------
__global__ __launch_bounds__(1024) void hist_kernel(
    const int* __restrict__ edge, const int* __restrict__ edge_num,
    unsigned short* __restrict__ histG)
{
    __shared__ unsigned int hist[HALF_R];      // 32 KB
    const int g = blockIdx.x;                  // [0, 512)
    const int half = g & 1;
    const int c = (g >> 1) & (CHUNKS - 1);
    const int b = g >> 7;
    const int t = threadIdx.x;
    const int en = edge_num[b];
    const int e0 = c * CHUNK_E;
    if (e0 >= en) return;                      // block-uniform

    for (int r = t; r < HALF_R; r += 1024) hist[r] = 0u;
    __syncthreads();

    const int2* ep = (const int2*)edge + (size_t)b * EE + e0;
    const int nAct = min(en - e0, CHUNK_E);
    for (int j = t; j < nAct; j += 1024) {
        const int2 e2 = ep[j];
        if ((e2.x >> 13) == half)              // row in my half
            atomicAdd(&hist[e2.x & (HALF_R - 1)], 1u);   // LDS atomic
    }
    __syncthreads();

    ushort2* out2 = (ushort2*)(histG + (size_t)(b * CHUNKS + c) * NN + half * HALF_R);
    for (int r2 = t; r2 < HALF_R / 2; r2 += 1024) {  // 4B coalesced stores
        ushort2 v;
        v.x = (unsigned short)hist[2 * r2];
        v.y = (unsigned short)hist[2 * r2 + 1];
        out2[r2] = v;
    }
}

// ---------------------------------------------------------------------------
// Kernel 2: fused MFMA + scan. Grid 1024 x 256 — R10's EXACT mfma geometry
// (waveId = blk*4 + w, bit-identical Wh/sc/sn). Blocks 0-255 additionally
// run R14's scan VERBATIM afterwards (their g is exactly the old scan
// blockIdx): exclusive prefix over the ACTIVE chunk counts, in-place histG
// -> u16 sat bases + cnt[row]. histG comes from dispatch 1 (kernel boundary
// -> visible). LDS = 0.5 KB (wc/wn) + 32 KB (scan tile) = 32.5 KB, which
// doesn't bind: grid 1024 on 256 CUs is 4 blocks/CU regardless.
// ---------------------------------------------------------------------------
__global__ __launch_bounds__(256) void mfma_scan_kernel(
    const float* __restrict__ h, const float* __restrict__ W,
    const float* __restrict__ a, const int* __restrict__ edge_num,
    unsigned short* __restrict__ Wh,
    float* __restrict__ sc, float* __restrict__ sn,
    unsigned short* __restrict__ histG, int* __restrict__ cnt)
{
    __shared__ float wc[FF], wn[FF];
    __shared__ unsigned short tile[CHUNKS][TILE_R];   // 32 KB (scan blocks only)
    const int t = threadIdx.x;
    const int lane = t & 63;
    const int m = lane & 15;
    const int q = lane >> 4;

    if (t < 128) {                         // threads 0-63: wc, 64-127: wn
        const int f = t & 63;
        const float* av = a + (t >> 6) * FF;
        float s = 0.0f;
        #pragma unroll 8
        for (int o = 0; o < FF; ++o)
            s = fmaf(av[o], W[o * FF + f], s);
        (t < 64 ? wc : wn)[f] = s;
    }

    // ---- B fragments: 4 n-tiles x 2 k-halves, in registers ---------------
    bf16x8 bfrag[4][2];
    #pragma unroll
    for (int nt = 0; nt < 4; ++nt) {
        const float* wr = W + (nt * 16 + m) * FF;
        #pragma unroll
        for (int kh = 0; kh < 2; ++kh) {
            const float4 v0 = *(const float4*)(wr + kh * 32 + q * 8);
            const float4 v1 = *(const float4*)(wr + kh * 32 + q * 8 + 4);
            bf16x8 b;
            b[0] = (__bf16)v0.x; b[1] = (__bf16)v0.y;
            b[2] = (__bf16)v0.z; b[3] = (__bf16)v0.w;
            b[4] = (__bf16)v1.x; b[5] = (__bf16)v1.y;
            b[6] = (__bf16)v1.z; b[7] = (__bf16)v1.w;
            bfrag[nt][kh] = b;
        }
    }

    __syncthreads();                       // wc/wn ready

    // ---- Phase A: one 16-row tile per wave (R10 formula, unchanged) ------
    {
        const int waveId = (blockIdx.x * 256 + t) >> 6;    // [0, 4096)
        const int R0 = waveId * 16;
        const float* hr = h + (size_t)(R0 + m) * FF;
        bf16x8 af[2];
        float s1 = 0.0f, s2 = 0.0f;        // partial sc/sn, 16 feats/lane
        #pragma unroll
        for (int kh = 0; kh < 2; ++kh) {
            const float4 v0 = *(const float4*)(hr + kh * 32 + q * 8);
            const float4 v1 = *(const float4*)(hr + kh * 32 + q * 8 + 4);
            bf16x8 aa;
            aa[0] = (__bf16)v0.x; aa[1] = (__bf16)v0.y;
            aa[2] = (__bf16)v0.z; aa[3] = (__bf16)v0.w;
            aa[4] = (__bf16)v1.x; aa[5] = (__bf16)v1.y;
            aa[6] = (__bf16)v1.z; aa[7] = (__bf16)v1.w;
            af[kh] = aa;
            const int fb = kh * 32 + q * 8;
            const float4 c0 = *(const float4*)&wc[fb];
            const float4 c1 = *(const float4*)&wc[fb + 4];
            const float4 n0 = *(const float4*)&wn[fb];
            const float4 n1 = *(const float4*)&wn[fb + 4];
            s1 = fmaf(v0.x, c0.x, fmaf(v0.y, c0.y, fmaf(v0.z, c0.z, fmaf(v0.w, c0.w, s1))));
            s1 = fmaf(v1.x, c1.x, fmaf(v1.y, c1.y, fmaf(v1.z, c1.z, fmaf(v1.w, c1.w, s1))));
            s2 = fmaf(v0.x, n0.x, fmaf(v0.y, n0.y, fmaf(v0.z, n0.z, fmaf(v0.w, n0.w, s2))));
            s2 = fmaf(v1.x, n1.x, fmaf(v1.y, n1.y, fmaf(v1.z, n1.z, fmaf(v1.w, n1.w, s2))));
        }
        s1 += __shfl_xor(s1, 16); s2 += __shfl_xor(s2, 16);
        s1 += __shfl_xor(s1, 32); s2 += __shfl_xor(s2, 32);
        if (lane < 16) { sc[R0 + m] = s1; sn[R0 + m] = s2; }

        #pragma unroll
        for (int nt = 0; nt < 4; ++nt) {
            f32x4 acc = {0.f, 0.f, 0.f, 0.f};
            acc = __builtin_amdgcn_mfma_f32_16x16x32_bf16(af[0], bfrag[nt][0], acc, 0, 0, 0);
            acc = __builtin_amdgcn_mfma_f32_16x16x32_bf16(af[1], bfrag[nt][1], acc, 0, 0, 0);
            #pragma unroll
            for (int i = 0; i < 4; ++i)
                Wh[(size_t)(R0 + q * 4 + i) * FF + nt * 16 + m] = f32_to_bf16(acc[i]);
        }
    }

    // ---- Phase B (blocks 0-255 only): R14 scan, verbatim ------------------
    const int g = blockIdx.x;
    if (g < 256) {                             // block-uniform
        const int b = g >> 6, tl = g & 63;
        const int r0 = tl * TILE_R;
        const int en = edge_num[b];
        const int nact = min((en + CHUNK_E - 1) / CHUNK_E, CHUNKS);

        for (int c = 0; c < nact; ++c)
            tile[c][t] = histG[(size_t)(b * CHUNKS + c) * NN + r0 + t];
        __syncthreads();

        unsigned int acc = 0;                  // thread t owns row r0+t
        for (int c = 0; c < nact; ++c) {
            const unsigned int v = tile[c][t];
            tile[c][t] = (unsigned short)(acc > 65535u ? 65535u : acc);
            acc += v;
        }
        cnt[b * NN + r0 + t] = (int)acc;

        for (int c = 0; c < nact; ++c)
            histG[(size_t)(b * CHUNKS + c) * NN + r0 + t] = tile[c][t];
    }
}

// ---------------------------------------------------------------------------
// Kernel 3: scatter + score, ROW-SPLIT (R14 version, verbatim). 512 blocks
// = (batch, chunk, half). slotA (32 KB) preloaded with scanned bases ->
// atomicAdd returns the dense slot; scL (32 KB) caches the half's sc slice.
// payload = (xe-hi18 | nbr-lo14).
// ---------------------------------------------------------------------------
__global__ __launch_bounds__(1024) void scatter_kernel(
    const int* __restrict__ edge, const int* __restrict__ edge_num,
    const unsigned short* __restrict__ baseG,
    const float* __restrict__ sc, const float* __restrict__ sn,
    const float* __restrict__ ew,
    unsigned int* __restrict__ payload)
{
    __shared__ unsigned int slotA[HALF_R];     // 32 KB
    __shared__ float scL[HALF_R];              // 32 KB
    const int g = blockIdx.x;                  // [0, 512)
    const int half = g & 1;
    const int c = (g >> 1) & (CHUNKS - 1);
    const int b = g >> 7;
    const int t = threadIdx.x;
    const int en = edge_num[b];
    const int e0 = c * CHUNK_E;
    if (e0 >= en) return;                      // block-uniform

    const int rbase = half * HALF_R;
    const ushort2* b2 = (const ushort2*)(baseG + (size_t)(b * CHUNKS + c) * NN + rbase);
    for (int r2 = t; r2 < HALF_R / 2; r2 += 1024) {  // coalesced
        const ushort2 v = b2[r2];
        slotA[2 * r2]     = v.x;
        slotA[2 * r2 + 1] = v.y;
    }
    const float* scH = sc + b * NN + rbase;
    for (int r = t; r < HALF_R; r += 1024)
        scL[r] = scH[r];
    __syncthreads();

    const int2* ep = (const int2*)edge + (size_t)b * EE + e0;
    const int nAct = min(en - e0, CHUNK_E);
    const float* snB = sn + b * NN;
    const float* ewB = ew + (size_t)b * EE + e0;   // coalesced: ewB[j]
    unsigned int* payB = payload + (size_t)b * NN * CAP;

    for (int j = t; j < nAct; j += 1024) {
        const int2 e2 = ep[j];
        if ((e2.x >> 13) != half) continue;    // row not in my half
        const int rl = e2.x & (HALF_R - 1);
        const float wgt = ewB[j];
        const float s0 = wgt * (scL[rl] + snB[e2.y]);
        const float s1 = s0 > 0.0f ? s0 : 0.01f * s0;
        const float xe = fminf(__expf(s1), 1000000.0f);
        const unsigned int slot = atomicAdd(&slotA[rl], 1u);     // base+rank
        if (slot < CAP)
            payB[(size_t)e2.x * CAP + slot] =
                ((__float_as_uint(xe) + 0x2000u) & 0xFFFFC000u) | (unsigned int)e2.y;
    }
}

// ---------------------------------------------------------------------------
// Kernel 4: gather v3 (proven R10 version, verbatim) — one row per 16-lane
// group (4 rows per wave). payload already holds packed (xe-hi18 | nbr-lo14).
// ---------------------------------------------------------------------------
__global__ __launch_bounds__(256) void gather_kernel(
    const int* __restrict__ cnt, const unsigned int* __restrict__ payload,
    const uint2* __restrict__ Wh2,             // bf16 quads
    float* __restrict__ out)
{
    const int bi = blockIdx.x;                 // 4096 blocks
    const int xcd = bi & 7;
    const int batch = xcd >> 1;                // 2 XCDs per batch
    const int within = ((bi >> 3) << 1) | (xcd & 1);   // [0, 1024)
    const int w = threadIdx.x >> 6;            // wave 0..3
    const int lane = threadIdx.x & 63;
    const int r = lane >> 4;                   // row within quad
    const int f = lane & 15;                   // feature quad
    const int gbase = lane & 48;               // first lane of my group
    const int rq = within * 4 + w;             // row-quad within batch
    const int row = batch * NN + rq * 4 + r;

    const unsigned int* pl = payload + (size_t)row * CAP;
    const uint2* WhB = Wh2 + (size_t)batch * NN * 16;

    int deg = cnt[row];
    unsigned int raw = pl[f];                  // unconditional, bounds-safe
    if (deg > CAP) deg = CAP;

    int jmax = deg;
    jmax = max(jmax, __shfl_xor(jmax, 16));
    jmax = max(jmax, __shfl_xor(jmax, 32));

    float a0 = 0.f, a1 = 0.f, a2 = 0.f, a3 = 0.f, pdsum = 0.f;

    for (int base = 0; base < jmax; base += 16) {
        const unsigned int p = (base + f < deg) ? raw : 0u;
        pdsum += __uint_as_float(p & 0xFFFFC000u);

        unsigned int rawN = 0u;
        if (base + 16 < jmax) rawN = pl[base + 16 + f];

        const int lim = min(16, jmax - base);
        for (int j4 = 0; j4 < lim; j4 += 4) {
            const unsigned int pv0 = __shfl(p, gbase + j4 + 0);
            const unsigned int pv1 = __shfl(p, gbase + j4 + 1);
            const unsigned int pv2 = __shfl(p, gbase + j4 + 2);
            const unsigned int pv3 = __shfl(p, gbase + j4 + 3);
            const uint2 w0 = WhB[(size_t)(pv0 & 0x3FFFu) * 16 + f];
            const uint2 w1 = WhB[(size_t)(pv1 & 0x3FFFu) * 16 + f];
            const uint2 w2 = WhB[(size_t)(pv2 & 0x3FFFu) * 16 + f];
            const uint2 w3 = WhB[(size_t)(pv3 & 0x3FFFu) * 16 + f];
            const float xe0 = __uint_as_float(pv0 & 0xFFFFC000u);
            const float xe1 = __uint_as_float(pv1 & 0xFFFFC000u);
            const float xe2 = __uint_as_float(pv2 & 0xFFFFC000u);
            const float xe3 = __uint_as_float(pv3 & 0xFFFFC000u);
            a0 = fmaf(xe0, __uint_as_float(w0.x << 16),         a0);
            a1 = fmaf(xe0, __uint_as_float(w0.x & 0xFFFF0000u), a1);
            a2 = fmaf(xe0, __uint_as_float(w0.y << 16),         a2);
            a3 = fmaf(xe0, __uint_as_float(w0.y & 0xFFFF0000u), a3);
            a0 = fmaf(xe1, __uint_as_float(w1.x << 16),         a0);
            a1 = fmaf(xe1, __uint_as_float(w1.x & 0xFFFF0000u), a1);
            a2 = fmaf(xe1, __uint_as_float(w1.y << 16),         a2);
            a3 = fmaf(xe1, __uint_as_float(w1.y & 0xFFFF0000u), a3);
            a0 = fmaf(xe2, __uint_as_float(w2.x << 16),         a0);
            a1 = fmaf(xe2, __uint_as_float(w2.x & 0xFFFF0000u), a1);
            a2 = fmaf(xe2, __uint_as_float(w2.y << 16),         a2);
            a3 = fmaf(xe2, __uint_as_float(w2.y & 0xFFFF0000u), a3);
            a0 = fmaf(xe3, __uint_as_float(w3.x << 16),         a0);
            a1 = fmaf(xe3, __uint_as_float(w3.x & 0xFFFF0000u), a1);
            a2 = fmaf(xe3, __uint_as_float(w3.y << 16),         a2);
            a3 = fmaf(xe3, __uint_as_float(w3.y & 0xFFFF0000u), a3);
        }
        raw = rawN;
    }

    pdsum += __shfl_xor(pdsum, 1);
    pdsum += __shfl_xor(pdsum, 2);
    pdsum += __shfl_xor(pdsum, 4);
    pdsum += __shfl_xor(pdsum, 8);

    const float inv = 1.0f / (1e-10f + pdsum);
    float4 o;
    o.x = fmaxf(a0 * inv, 0.0f);
    o.y = fmaxf(a1 * inv, 0.0f);
    o.z = fmaxf(a2 * inv, 0.0f);
    o.w = fmaxf(a3 * inv, 0.0f);
    ((float4*)out)[(size_t)row * 16 + f] = o;
}

extern "C" void kernel_launch(void* const* d_in, const int* in_sizes, int n_in,
                              void* d_out, int out_size, void* d_ws, size_t ws_size,
                              hipStream_t stream)
{
    const float* h        = (const float*)d_in[0];   // (B,N,F) f32
    const int*   edge     = (const int*)  d_in[1];   // (B,E,2) i32
    const int*   edge_num = (const int*)  d_in[2];   // (B,)    i32
    const float* ew       = (const float*)d_in[3];   // (B,E)   f32
    const float* W        = (const float*)d_in[4];   // (F,F)   f32
    const float* a        = (const float*)d_in[5];   // (1,2F)  f32
    float* out = (float*)d_out;                      // (B,N,F) f32

    // workspace layout — ~33 MB of the 256 MB d_ws
    unsigned short* Wh = (unsigned short*)d_ws;                 // 8 MB
    float* sc        = (float*)(Wh + (size_t)BB * NN * FF);     // 256 KB
    float* sn        = sc + ROWS;                               // 256 KB
    int*   cnt       = (int*)(sn + ROWS);                       // 256 KB
    unsigned int* payload = (unsigned int*)(cnt + ROWS);        // 16 MB
    unsigned short* histG = (unsigned short*)(payload + (size_t)ROWS * CAP); // 8 MB

    hist_kernel<<<BB * CHUNKS * 2, 1024, 0, stream>>>(edge, edge_num, histG);

    mfma_scan_kernel<<<1024, 256, 0, stream>>>(h, W, a, edge_num,
                                               Wh, sc, sn, histG, cnt);

    scatter_kernel<<<BB * CHUNKS * 2, 1024, 0, stream>>>(edge, edge_num, histG,
                                                         sc, sn, ew, payload);

    gather_kernel<<<4096, 256, 0, stream>>>(cnt, payload,
                                            (const uint2*)Wh, out);
}